// Round 11
// baseline (285.336 us; speedup 1.0000x reference)
//
#include <hip/hip_runtime.h>

#define BLKE 524288      // 128*64*64
#define VOLE 4194304     // 256*128*128
#define TCROP 2097152    // 128*128*128 (t<128 compact complex volume)
#define PI2 6.283185307179586476925286766559

__device__ __forceinline__ float2 cmulf(float2 a, float2 b){
  return make_float2(a.x*b.x - a.y*b.y, a.x*b.y + a.y*b.x);
}
__device__ __forceinline__ float waveSum(float v){
  #pragma unroll
  for (int o=32;o;o>>=1) v += __shfl_xor(v,o);
  return v;
}
__device__ __forceinline__ float waveMaxf(float v){
  #pragma unroll
  for (int o=32;o;o>>=1) v = fmaxf(v,__shfl_xor(v,o));
  return v;
}
__device__ __forceinline__ float waveMinf(float v){
  #pragma unroll
  for (int o=32;o;o>>=1) v = fminf(v,__shfl_xor(v,o));
  return v;
}

// Reduce pA[kappa][256][5] redundantly (identical FP order in every block).
__device__ __forceinline__ void bcastReduce5(const float* __restrict__ pA, int kap,
    float& sum, float& mnl, float& mxl, float& mnh, float& mxh, float* sm /*>=20*/){
  int tid = threadIdx.x;
  const float* q = pA + kap*1280 + tid*5;
  float s = q[0], a = q[1], b = q[2], c = q[3], d = q[4];
  s = waveSum(s); a = waveMinf(a); b = waveMaxf(b); c = waveMinf(c); d = waveMaxf(d);
  if ((tid&63)==0){ int w = tid>>6; sm[w]=s; sm[4+w]=a; sm[8+w]=b; sm[12+w]=c; sm[16+w]=d; }
  __syncthreads();
  sum = sm[0]+sm[1]+sm[2]+sm[3];
  mnl = fminf(fminf(sm[4],sm[5]),fminf(sm[6],sm[7]));
  mxl = fmaxf(fmaxf(sm[8],sm[9]),fmaxf(sm[10],sm[11]));
  mnh = fminf(fminf(sm[12],sm[13]),fminf(sm[14],sm[15]));
  mxh = fmaxf(fmaxf(sm[16],sm[17]),fmaxf(sm[18],sm[19]));
}

__device__ __forceinline__ float bcastSum256(const float* __restrict__ p, float* sm /*>=4*/){
  int tid = threadIdx.x;
  float s = waveSum(p[tid]);
  if ((tid&63)==0) sm[tid>>6] = s;
  __syncthreads();
  return sm[0]+sm[1]+sm[2]+sm[3];
}

// ============ D1: attention pass A (blocks 0..511) || kM (512..639) ==========
__global__ void __launch_bounds__(256) kD1(const float* __restrict__ mtx,
                                           const float* __restrict__ wave,
                                           float* __restrict__ M,
                                           const float* __restrict__ Kr,
                                           const float* __restrict__ Ki,
                                           float* __restrict__ Lw, float* __restrict__ Hw,
                                           float* __restrict__ pA){
  __shared__ float spe[128];
  __shared__ float sm[20];
  int bid = blockIdx.x;
  int tid = threadIdx.x;
  if (bid < 512){
    int kap = bid >> 8, bx = bid & 255;
    const float* K = kap ? Ki : Kr;
    if (tid < 128) spe[tid] = sinf((float)tid);
    __syncthreads();
    float sum=0.f, mnl=3.4e38f, mxl=-3.4e38f, mnh=3.4e38f, mxh=-3.4e38f;
    int base = bx*256 + tid;
    #pragma unroll
    for (int it = 0; it < 8; it++){
      int e = base + it*65536;
      int tau = e >> 12, rem = e & 4095, eta = rem >> 6, om = rem & 63;
      float pe = spe[tau];
      float lo = K[(size_t)((tau+192)&255)*16384 + ((eta+96)&127)*128 + ((om+96)&127)];
      float hi = K[(size_t)(tau+64)*16384 + (eta+32)*128 + (om+32)];
      sum += lo;
      float lp = lo+pe, hp = hi+pe;
      Lw[kap*BLKE + e] = lp;
      Hw[kap*BLKE + e] = hp;
      mnl=fminf(mnl,lp); mxl=fmaxf(mxl,lp);
      mnh=fminf(mnh,hp); mxh=fmaxf(mxh,hp);
    }
    sum = waveSum(sum); mnl=waveMinf(mnl); mxl=waveMaxf(mxl); mnh=waveMinf(mnh); mxh=waveMaxf(mxh);
    if ((tid&63)==0){ int w=tid>>6; sm[w]=sum; sm[4+w]=mnl; sm[8+w]=mxl; sm[12+w]=mnh; sm[16+w]=mxh; }
    __syncthreads();
    if (tid==0){
      float* o = pA + kap*1280 + bx*5;
      o[0] = sm[0]+sm[1]+sm[2]+sm[3];
      o[1] = fminf(fminf(sm[4],sm[5]),fminf(sm[6],sm[7]));
      o[2] = fmaxf(fmaxf(sm[8],sm[9]),fmaxf(sm[10],sm[11]));
      o[3] = fminf(fminf(sm[12],sm[13]),fminf(sm[14],sm[15]));
      o[4] = fmaxf(fmaxf(sm[16],sm[17]),fmaxf(sm[18],sm[19]));
    }
  } else {
    int idx = (bid-512)*256 + tid;      // 32768 = 2*128*128
    int o = idx >> 14, r = idx & 16383;
    int t = r >> 7, s = r & 127;
    float acc = 0.f;
    int mlo = s-31; if (mlo < 0) mlo = 0;
    int mhi = s+31; if (mhi > 127) mhi = 127;
    for (int m = mlo; m <= mhi; m++) acc += mtx[t*128+m]*wave[o*63 + (s-m+31)];
    M[idx] = acc;
  }
}

// ============ D2: pass B (0..511) || kTmp (512..1023) ========================
__global__ void __launch_bounds__(256) kD2(const float* __restrict__ feat,
                                           const float* __restrict__ M,
                                           float* __restrict__ tmp,
                                           const float* __restrict__ pA,
                                           const float* __restrict__ Lw,
                                           float* __restrict__ pB,
                                           const float* cw, const float* cb){
  __shared__ __align__(16) char smem[16640];
  __shared__ float sm[20], smo[4];
  int bid = blockIdx.x;
  int tid = threadIdx.x;
  if (bid < 512){
    int kap = bid >> 8, bx = bid & 255;
    float sum,mnl,mxl,mnh,mxh;
    bcastReduce5(pA,kap,sum,mnl,mxl,mnh,mxh,sm);
    float w = cw[0], b = cb[0];
    float s1 = w*(sum*(1.0f/BLKE)) + b;
    float a1 = s1*w, c1 = s1*b;
    float mx = (a1>=0.f) ? a1*mxl+c1 : a1*mnl+c1;
    float acc = 0.f;
    int base = kap*BLKE + bx*256 + tid;
    #pragma unroll
    for (int it = 0; it < 8; it++){
      float lp = Lw[base + it*65536];
      acc += expf(a1*lp + c1 - mx);
    }
    acc = waveSum(acc);
    if ((tid&63)==0) smo[tid>>6] = acc;
    __syncthreads();
    if (tid==0) pB[kap*256 + bx] = smo[0]+smo[1]+smo[2]+smo[3];
  } else {
    int e = bid - 512;                  // 512 : b(2) x tt(4) x xt(64)
    int b = e >> 8, tt = (e >> 6) & 3, xt = e & 63;
    float (*LF)[64] = (float(*)[64])smem;
    float (*LM)[32][33] = (float(*)[32][33])(smem + 8192);
    int xx = tid & 63, tq = tid >> 6;
    float acc0[8] = {}, acc1[8] = {};
    const float* fb = feat + (size_t)b*BLKE;
    for (int sb = 0; sb < 4; sb++){
      #pragma unroll
      for (int j = 0; j < 8; j++){
        int idx = tid + j*256; int s = idx >> 6, x = idx & 63;
        LF[s][x] = fb[(size_t)(sb*32+s)*4096 + xt*64 + x];
      }
      #pragma unroll
      for (int j = 0; j < 8; j++){
        int idx = tid + j*256; int o = idx >> 10, r = idx & 1023;
        int trow = r >> 5, s = r & 31;
        LM[o][trow][s] = M[o*16384 + (tt*32+trow)*128 + sb*32+s];
      }
      __syncthreads();
      for (int s = 0; s < 32; s++){
        float f = LF[s][xx];
        #pragma unroll
        for (int i = 0; i < 8; i++){
          acc0[i] += LM[0][tq*8+i][s]*f;
          acc1[i] += LM[1][tq*8+i][s]*f;
        }
      }
      __syncthreads();
    }
    #pragma unroll
    for (int i = 0; i < 8; i++){
      int t = tt*32 + tq*8 + i;
      tmp[(size_t)(0*2+b)*BLKE + (size_t)t*4096 + xt*64+xx] = acc0[i];
      tmp[(size_t)(1*2+b)*BLKE + (size_t)t*4096 + xt*64+xx] = acc1[i];
    }
  }
}

// ============ D3: pass C (0..511) || kF1 (512..4607) =========================
__global__ void __launch_bounds__(256) kD3(const float* __restrict__ tmp,
                                           float2* __restrict__ Z2,
                                           const float* __restrict__ pA,
                                           const float* __restrict__ pB,
                                           const float* __restrict__ Lw,
                                           float* __restrict__ pC,
                                           const float* cw, const float* cb){
  __shared__ __align__(16) char smem[8832];
  __shared__ float sm[20], smB[4], smo[4];
  int bid = blockIdx.x;
  int tid = threadIdx.x;
  if (bid < 512){
    int kap = bid >> 8, bx = bid & 255;
    float sum,mnl,mxl,mnh,mxh;
    bcastReduce5(pA,kap,sum,mnl,mxl,mnh,mxh,sm);
    float d1 = bcastSum256(pB + kap*256, smB);
    float w = cw[0], b = cb[0];
    float s1 = w*(sum*(1.0f/BLKE)) + b;
    float a1 = s1*w, c1 = s1*b;
    float mx = (a1>=0.f) ? a1*mxl+c1 : a1*mnl+c1;
    float invd = 1.0f/d1;
    float acc = 0.f;
    int base = kap*BLKE + bx*256 + tid;
    #pragma unroll
    for (int it = 0; it < 8; it++){
      float lp = Lw[base + it*65536];
      float p = expf(a1*lp + c1 - mx)*invd;
      acc += lp/(1.f + expf(-p));
    }
    acc = waveSum(acc);
    if ((tid&63)==0) smo[tid>>6] = acc;
    __syncthreads();
    if (tid==0) pC[kap*256 + bx] = smo[0]+smo[1]+smo[2]+smo[3];
  } else {
    int e = bid - 512;                  // 4096 : b(2) x 2048 line-groups
    int b = e >> 11, bx = e & 2047;
    float2 (*bA)[130] = (float2(*)[130])smem;
    float2 (*bB)[130] = (float2(*)[130])(smem + 4160);
    float2* tw = (float2*)(smem + 8320);
    if (tid < 64){
      double ang = -PI2 * (double)tid / 128.0;
      tw[tid] = make_float2((float)cos(ang), (float)sin(ang));
    }
    int l = tid >> 6, lane = tid & 63;
    int line = bx*4 + l;
    int t = line >> 6, h = line & 63;
    const float* pc = tmp + (size_t)b*BLKE + (size_t)t*4096 + h*64;
    const float* ps = tmp + (size_t)(2+b)*BLKE + (size_t)t*4096 + h*64;
    bA[l][lane] = make_float2(pc[lane], ps[lane]);
    bA[l][lane+64] = make_float2(0.f, 0.f);
    __syncthreads();
    float2 (*src)[130] = bA, (*dst)[130] = bB;
    int m = 1;
    #pragma unroll
    for (int st = 0; st < 7; st++){
      int i = lane;
      int jm = i & ~(m-1);
      float2 a = src[l][i], b2 = src[l][i+64];
      float2 s = make_float2(a.x+b2.x, a.y+b2.y);
      float2 d = make_float2(a.x-b2.x, a.y-b2.y);
      dst[l][i+jm]   = s;
      dst[l][i+jm+m] = cmulf(d, tw[jm]);
      __syncthreads();
      float2 (*tp)[130] = src; src = dst; dst = tp;
      m <<= 1;
    }
    float2* outp = Z2 + (size_t)b*TCROP + (size_t)t*16384 + (size_t)h*128;
    outp[lane]    = src[l][lane];
    outp[lane+64] = src[l][lane+64];
  }
}

// ============ D4: pass D (0..511) || kHf (512..2559) =========================
__global__ void __launch_bounds__(256) kD4(float2* __restrict__ Z2,
                                           const float* __restrict__ pA,
                                           const float* __restrict__ pC,
                                           const float* __restrict__ Hw,
                                           float* __restrict__ pD,
                                           const float* cw, const float* cb){
  __shared__ __align__(16) char smem[33792];
  __shared__ float sm[20], smC[4], smo[4];
  int bid = blockIdx.x;
  int tid = threadIdx.x;
  if (bid < 512){
    int kap = bid >> 8, bx = bid & 255;
    float sum,mnl,mxl,mnh,mxh;
    bcastReduce5(pA,kap,sum,mnl,mxl,mnh,mxh,sm);
    float sl2 = bcastSum256(pC + kap*256, smC);
    float w = cw[0], b = cb[0];
    float s2 = w*(sl2*(1.0f/BLKE)) + b;
    float a2 = s2*w, c2 = s2*b;
    float mx = (a2>=0.f) ? a2*mxh+c2 : a2*mnh+c2;
    float acc = 0.f;
    int base = kap*BLKE + bx*256 + tid;
    #pragma unroll
    for (int it = 0; it < 8; it++){
      float hp = Hw[base + it*65536];
      acc += expf(a2*hp + c2 - mx);
    }
    acc = waveSum(acc);
    if ((tid&63)==0) smo[tid>>6] = acc;
    __syncthreads();
    if (tid==0) pD[kap*256 + bx] = smo[0]+smo[1]+smo[2]+smo[3];
  } else {
    int e = bid - 512;                  // 2048 : b(2) x 1024
    int b = e >> 10, bx = e & 1023;
    float2 (*bA)[130] = (float2(*)[130])smem;
    float2 (*bB)[130] = (float2(*)[130])(smem + 16640);
    float2* tw = (float2*)(smem + 33280);
    if (tid < 64){
      double ang = -PI2 * (double)tid / 128.0;
      tw[tid] = make_float2((float)cos(ang), (float)sin(ang));
    }
    float2* Z = Z2 + (size_t)b*TCROP;
    int t = bx >> 3; int w0 = (bx & 7) << 4;
    size_t base = (size_t)t*16384 + w0;
    #pragma unroll
    for (int q = 0; q < 4; q++){
      int idx = q*256 + tid; int wl = idx & 15, hh = idx >> 4;
      bA[wl][hh] = Z[base + (size_t)hh*128 + wl];
      bA[wl][hh+64] = make_float2(0.f, 0.f);
    }
    __syncthreads();
    float2 (*src)[130] = bA, (*dst)[130] = bB;
    int m = 1;
    #pragma unroll
    for (int st = 0; st < 7; st++){
      #pragma unroll
      for (int q = 0; q < 4; q++){
        int g = q*256 + tid; int li = g >> 6; int i = g & 63;
        int jm = i & ~(m-1);
        float2 a = src[li][i], b2 = src[li][i+64];
        float2 s = make_float2(a.x+b2.x, a.y+b2.y);
        float2 d = make_float2(a.x-b2.x, a.y-b2.y);
        dst[li][i+jm]   = s;
        dst[li][i+jm+m] = cmulf(d, tw[jm]);
      }
      __syncthreads();
      float2 (*tp)[130] = src; src = dst; dst = tp;
      m <<= 1;
    }
    #pragma unroll
    for (int q = 0; q < 8; q++){
      int idx = q*256 + tid; int wl = idx & 15, hh = idx >> 4;
      Z[base + (size_t)hh*128 + wl] = src[wl][hh];
    }
  }
}

// ---------------- attention helpers ----------------
__device__ __forceinline__ float attnv(float v, float a, float c, float mx, float invd){
  float p = expf(a*v + c - mx)*invd;
  return v / (1.f + expf(-p));
}
__device__ __forceinline__ float2 wcAt(int t, int h, int w,
                                       const float* __restrict__ Kr, const float* __restrict__ Ki,
                                       const float* spe, const float* P){
  size_t off = (size_t)t*16384 + (size_t)h*128 + w;
  float kr = Kr[off], ki = Ki[off];
  bool center = (t>=64 && t<192) && (h>=32 && h<96) && (w>=32 && w<96);
  int tc = (t+64)&255, hc = (h+32)&127, wc = (w+32)&127;
  bool corner = (tc<128) && (hc<64) && (wc<64);
  float2 o;
  if (center){
    float pe = spe[t-64];
    o.x = attnv(kr+pe, P[4],  P[5],  P[6],  P[7]);
    o.y = attnv(ki+pe, P[12], P[13], P[14], P[15]);
  } else if (corner){
    float pe = spe[tc];
    o.x = attnv(kr+pe, P[0], P[1],  P[2],  P[3]);
    o.y = attnv(ki+pe, P[8], P[9],  P[10], P[11]);
  } else {
    o.x = kr; o.y = ki;
  }
  return o;
}

// ======== D5: finalize scalars inline (redundant per block) + Wc volume ======
__global__ void __launch_bounds__(256) kWcF(const float* __restrict__ Kr,
                                            const float* __restrict__ Ki,
                                            const float* __restrict__ pA,
                                            const float* __restrict__ pB,
                                            const float* __restrict__ pC,
                                            const float* __restrict__ pD,
                                            const float* cw, const float* cb,
                                            float2* __restrict__ Wc){
  __shared__ float spe[128];
  __shared__ float P[16];
  __shared__ float sm[20], smB[4], smC[4], smD[4];
  int tid = threadIdx.x;
  if (tid < 128) spe[tid] = sinf((float)tid);
  for (int kap = 0; kap < 2; kap++){
    if (kap) __syncthreads();
    float sum,mnl,mxl,mnh,mxh;
    bcastReduce5(pA,kap,sum,mnl,mxl,mnh,mxh,sm);
    float d1  = bcastSum256(pB + kap*256, smB);
    float sl2 = bcastSum256(pC + kap*256, smC);
    float d2  = bcastSum256(pD + kap*256, smD);
    if (tid==0){
      float w = cw[0], b = cb[0];
      float s1 = w*(sum*(1.0f/BLKE)) + b;
      float a1 = s1*w, c1 = s1*b;
      float mx1 = (a1>=0.f) ? a1*mxl+c1 : a1*mnl+c1;
      float s2 = w*(sl2*(1.0f/BLKE)) + b;
      float a2 = s2*w, c2 = s2*b;
      float mx2 = (a2>=0.f) ? a2*mxh+c2 : a2*mnh+c2;
      float* Q = P + kap*8;
      Q[0]=a1; Q[1]=c1; Q[2]=mx1; Q[3]=1.0f/d1;
      Q[4]=a2; Q[5]=c2; Q[6]=mx2; Q[7]=1.0f/d2;
    }
  }
  __syncthreads();
  #pragma unroll
  for (int q = 0; q < 4; q++){
    int idx = blockIdx.x*1024 + q*256 + tid;   // VOLE over 4096 blocks
    int t = idx >> 14, r = idx & 16383, h = r >> 7, w = r & 127;
    Wc[idx] = wcAt(t, h, w, Kr, Ki, spe, P);
  }
}

// ---- fused fwd-T(256) + multiply + 2x inv-T, radix-4 in-place --------------
// Multipliers prefetched into registers from the single Wc stream:
// U-set before the forward FFT, V-set before the first inverse FFT.
__global__ void __launch_bounds__(256) kTfused(const float2* __restrict__ Z2,
                                               float2* __restrict__ U2,
                                               float2* __restrict__ V2,
                                               const float2* __restrict__ Wc){
  __shared__ float2 buf[16][259];
  __shared__ float2 tw[256];
  int tid = threadIdx.x;
  {
    double ang = -PI2 * (double)tid / 256.0;
    tw[tid] = make_float2((float)cos(ang), (float)sin(ang));
  }
  int b = blockIdx.y;
  int bid = blockIdx.x;                 // 1024 : 128 h x 8 w-tiles(16)
  int h = bid >> 3, w0 = (bid & 7) << 4;
  int wl = tid & 15, pq = tid >> 4;
  int wg = w0 + wl;
  const float2* Z = Z2 + (size_t)b*TCROP;
  size_t gbase = (size_t)h*128 + wg;
  // ---- prefetch U-path multipliers (consumed after fwd FFT) ----
  float2 wcu[16];
  #pragma unroll
  for (int q = 0; q < 16; q++){
    int p = q*16 + pq;
    int kt = ((p&3)<<6) | (((p>>2)&3)<<4) | (((p>>4)&3)<<2) | ((p>>6)&3);
    wcu[q] = Wc[(size_t)kt*16384 + gbase];
  }
  #pragma unroll
  for (int q = 0; q < 8; q++){
    int p = q*16 + pq;
    buf[wl][p] = Z[(size_t)p*16384 + gbase];
    buf[wl][p+128] = make_float2(0.f, 0.f);
  }
  __syncthreads();
  // ---- forward radix-4 DIF, 4 stages ----
  #pragma unroll
  for (int st = 0; st < 4; st++){
    const int Q = 64 >> (2*st);
    const int f = 1 << (2*st);
    #pragma unroll
    for (int it = 0; it < 4; it++){
      int u = pq + 16*it;
      int j = u & (Q-1);
      int seg = u >> (6 - 2*st);
      int base = (seg << (8 - 2*st)) + j;
      float2 a0 = buf[wl][base];
      float2 a1 = buf[wl][base+Q];
      float2 a2 = buf[wl][base+2*Q];
      float2 a3 = buf[wl][base+3*Q];
      float2 t0 = make_float2(a0.x+a2.x, a0.y+a2.y);
      float2 t1 = make_float2(a0.x-a2.x, a0.y-a2.y);
      float2 t2 = make_float2(a1.x+a3.x, a1.y+a3.y);
      float2 t3 = make_float2(a1.x-a3.x, a1.y-a3.y);
      float2 z0 = make_float2(t0.x+t2.x, t0.y+t2.y);
      float2 z2 = make_float2(t0.x-t2.x, t0.y-t2.y);
      float2 z1 = make_float2(t1.x+t3.y, t1.y-t3.x);
      float2 z3 = make_float2(t1.x-t3.y, t1.y+t3.x);
      buf[wl][base]     = z0;
      buf[wl][base+Q]   = cmulf(z1, tw[f*j]);
      buf[wl][base+2*Q] = cmulf(z2, tw[2*f*j]);
      buf[wl][base+3*Q] = cmulf(z3, tw[3*f*j]);
    }
    __syncthreads();
  }
  float2 rg[16];
  #pragma unroll
  for (int q = 0; q < 16; q++) rg[q] = buf[wl][q*16 + pq];
  // ---- multiply U = X * Wc(kt) ----
  #pragma unroll
  for (int q = 0; q < 16; q++){
    int p = q*16 + pq;
    buf[wl][p] = cmulf(rg[q], wcu[q]);
  }
  // ---- prefetch V-path multipliers (consumed after first inverse FFT) ----
  float2 wcv[16];
  #pragma unroll
  for (int q = 0; q < 16; q++){
    int p = q*16 + pq;
    int kt = ((p&3)<<6) | (((p>>2)&3)<<4) | (((p>>4)&3)<<2) | ((p>>6)&3);
    int tm = (256-kt)&255, hm = (128-h)&127, wm = (128-wg)&127;
    wcv[q] = Wc[(size_t)tm*16384 + (size_t)hm*128 + wm];
  }
  __syncthreads();
  // ---- inverse radix-4 DIT, 4 stages ----
  #pragma unroll
  for (int st = 0; st < 4; st++){
    const int Q = 1 << (2*st);
    const int f = 64 >> (2*st);
    #pragma unroll
    for (int it = 0; it < 4; it++){
      int u = pq + 16*it;
      int j = u & (Q-1);
      int seg = u >> (2*st);
      int base = (seg << (2*st + 2)) + j;
      float2 w1 = tw[f*j], w2 = tw[2*f*j], w3 = tw[3*f*j];
      float2 a0 = buf[wl][base];
      float2 r1 = buf[wl][base+Q];
      float2 r2 = buf[wl][base+2*Q];
      float2 r3 = buf[wl][base+3*Q];
      float2 b1 = make_float2(r1.x*w1.x + r1.y*w1.y, r1.y*w1.x - r1.x*w1.y);
      float2 b2 = make_float2(r2.x*w2.x + r2.y*w2.y, r2.y*w2.x - r2.x*w2.y);
      float2 b3 = make_float2(r3.x*w3.x + r3.y*w3.y, r3.y*w3.x - r3.x*w3.y);
      float2 t0 = make_float2(a0.x+b2.x, a0.y+b2.y);
      float2 t1 = make_float2(a0.x-b2.x, a0.y-b2.y);
      float2 t2 = make_float2(b1.x+b3.x, b1.y+b3.y);
      float2 t3 = make_float2(b1.x-b3.x, b1.y-b3.y);
      buf[wl][base]     = make_float2(t0.x+t2.x, t0.y+t2.y);
      buf[wl][base+Q]   = make_float2(t1.x-t3.y, t1.y+t3.x);
      buf[wl][base+2*Q] = make_float2(t0.x-t2.x, t0.y-t2.y);
      buf[wl][base+3*Q] = make_float2(t1.x+t3.y, t1.y-t3.x);
    }
    __syncthreads();
  }
  float2* Uo = U2 + (size_t)b*TCROP;
  #pragma unroll
  for (int q = 0; q < 8; q++){
    int p = q*16 + pq;
    Uo[(size_t)p*16384 + gbase] = buf[wl][p];
  }
  // ---- multiply V' = X * conj(Wc(-kt)) ----
  #pragma unroll
  for (int q = 0; q < 16; q++){
    int p = q*16 + pq;
    float2 wc = wcv[q];
    wc.y = -wc.y;
    buf[wl][p] = cmulf(rg[q], wc);
  }
  __syncthreads();
  // ---- inverse radix-4 DIT again ----
  #pragma unroll
  for (int st = 0; st < 4; st++){
    const int Q = 1 << (2*st);
    const int f = 64 >> (2*st);
    #pragma unroll
    for (int it = 0; it < 4; it++){
      int u = pq + 16*it;
      int j = u & (Q-1);
      int seg = u >> (2*st);
      int base = (seg << (2*st + 2)) + j;
      float2 w1 = tw[f*j], w2 = tw[2*f*j], w3 = tw[3*f*j];
      float2 a0 = buf[wl][base];
      float2 r1 = buf[wl][base+Q];
      float2 r2 = buf[wl][base+2*Q];
      float2 r3 = buf[wl][base+3*Q];
      float2 b1 = make_float2(r1.x*w1.x + r1.y*w1.y, r1.y*w1.x - r1.x*w1.y);
      float2 b2 = make_float2(r2.x*w2.x + r2.y*w2.y, r2.y*w2.x - r2.x*w2.y);
      float2 b3 = make_float2(r3.x*w3.x + r3.y*w3.y, r3.y*w3.x - r3.x*w3.y);
      float2 t0 = make_float2(a0.x+b2.x, a0.y+b2.y);
      float2 t1 = make_float2(a0.x-b2.x, a0.y-b2.y);
      float2 t2 = make_float2(b1.x+b3.x, b1.y+b3.y);
      float2 t3 = make_float2(b1.x-b3.x, b1.y-b3.y);
      buf[wl][base]     = make_float2(t0.x+t2.x, t0.y+t2.y);
      buf[wl][base+Q]   = make_float2(t1.x-t3.y, t1.y+t3.x);
      buf[wl][base+2*Q] = make_float2(t0.x-t2.x, t0.y-t2.y);
      buf[wl][base+3*Q] = make_float2(t1.x+t3.y, t1.y-t3.x);
    }
    __syncthreads();
  }
  float2* Vo = V2 + (size_t)b*TCROP;
  #pragma unroll
  for (int q = 0; q < 8; q++){
    int p = q*16 + pq;
    Vo[(size_t)p*16384 + gbase] = buf[wl][p];
  }
}

// ---------------- H-axis inverse (N=128) on compact buffers: grid (1024,b,uv)
__global__ void __launch_bounds__(256) kHi(float2* __restrict__ U2, float2* __restrict__ V2){
  __shared__ float2 bA[16][130], bB[16][130], tw[64];
  int tid = threadIdx.x;
  if (tid < 64){
    double ang = PI2 * (double)tid / 128.0;
    tw[tid] = make_float2((float)cos(ang), (float)sin(ang));
  }
  float2* Z = (blockIdx.z ? V2 : U2) + (size_t)blockIdx.y*TCROP;
  int bid = blockIdx.x;
  int t = bid >> 3; int w0 = (bid & 7) << 4;
  size_t base = (size_t)t*16384 + w0;
  #pragma unroll
  for (int q = 0; q < 8; q++){
    int idx = q*256 + tid; int wl = idx & 15, hh = idx >> 4;
    bA[wl][hh] = Z[base + (size_t)hh*128 + wl];
  }
  __syncthreads();
  float2 (*src)[130] = bA, (*dst)[130] = bB;
  int m = 1;
  #pragma unroll
  for (int st = 0; st < 7; st++){
    #pragma unroll
    for (int q = 0; q < 4; q++){
      int g = q*256 + tid; int li = g >> 6; int i = g & 63;
      int jm = i & ~(m-1);
      float2 a = src[li][i], b2 = src[li][i+64];
      float2 s = make_float2(a.x+b2.x, a.y+b2.y);
      float2 d = make_float2(a.x-b2.x, a.y-b2.y);
      dst[li][i+jm]   = s;
      dst[li][i+jm+m] = cmulf(d, tw[jm]);
    }
    __syncthreads();
    float2 (*tp)[130] = src; src = dst; dst = tp;
    m <<= 1;
  }
  #pragma unroll
  for (int q = 0; q < 4; q++){
    int idx = q*256 + tid; int wl = idx & 15, hh = idx >> 4;   // hh < 64
    Z[base + (size_t)hh*128 + wl] = src[wl][hh];
  }
}

// -- fused W-axis inverse + combine: per line FFT U then V; s=y*conj(v)*sc^2 --
__global__ void __launch_bounds__(256) kI3C(const float2* __restrict__ U2,
                                            const float2* __restrict__ V2,
                                            float* __restrict__ sq){
  __shared__ float2 bA[4][130], bB[4][130], tw[64];
  int tid = threadIdx.x;
  if (tid < 64){
    double ang = PI2 * (double)tid / 128.0;
    tw[tid] = make_float2((float)cos(ang), (float)sin(ang));
  }
  int b = blockIdx.y;
  int l = tid >> 6, lane = tid & 63;
  int line = blockIdx.x*4 + l;         // t<128, h<64
  int t = line >> 6, h = line & 63;
  size_t off = (size_t)b*TCROP + (size_t)t*16384 + (size_t)h*128;
  bA[l][lane]    = U2[off + lane];
  bA[l][lane+64] = U2[off + lane + 64];
  __syncthreads();
  float2 (*src)[130] = bA, (*dst)[130] = bB;
  int m = 1;
  #pragma unroll
  for (int st = 0; st < 7; st++){
    int i = lane;
    int jm = i & ~(m-1);
    float2 a = src[l][i], b2 = src[l][i+64];
    float2 s = make_float2(a.x+b2.x, a.y+b2.y);
    float2 d = make_float2(a.x-b2.x, a.y-b2.y);
    dst[l][i+jm]   = s;
    dst[l][i+jm+m] = cmulf(d, tw[jm]);
    __syncthreads();
    float2 (*tp)[130] = src; src = dst; dst = tp;
    m <<= 1;
  }
  float2 y = src[l][lane];
  dst[l][lane]    = V2[off + lane];
  dst[l][lane+64] = V2[off + lane + 64];
  __syncthreads();
  src = dst; dst = (src == bA) ? bB : bA;
  m = 1;
  #pragma unroll
  for (int st = 0; st < 7; st++){
    int i = lane;
    int jm = i & ~(m-1);
    float2 a = src[l][i], b2 = src[l][i+64];
    float2 s = make_float2(a.x+b2.x, a.y+b2.y);
    float2 d = make_float2(a.x-b2.x, a.y-b2.y);
    dst[l][i+jm]   = s;
    dst[l][i+jm+m] = cmulf(d, tw[jm]);
    __syncthreads();
    float2 (*tp)[130] = src; src = dst; dst = tp;
    m <<= 1;
  }
  float2 v = src[l][lane];
  const float sc = 1.0f/(float)VOLE;
  const float sc2 = sc*sc;
  float2 s = cmulf(y, make_float2(v.x, -v.y));
  s.x *= sc2; s.y *= sc2;
  float mag = 0.5f*(sqrtf(s.x*s.x + s.y*s.y) + s.x);
  mag = fmaxf(mag, 0.f);
  sq[(size_t)b*BLKE + (size_t)t*4096 + h*64 + lane] = sqrtf(mag);
}

// ---------------- out[b][t][x] = sum_m mtxi[t][m]*sq[b][m][x] ----------------
__global__ void __launch_bounds__(256) kOut(const float* __restrict__ sq,
                                            const float* __restrict__ mtxi,
                                            float* __restrict__ out){
  __shared__ float LF[32][64];
  __shared__ float LM[32][33];
  int b = blockIdx.z, tt = blockIdx.y, xt = blockIdx.x;
  int tid = threadIdx.x;
  int xx = tid & 63, tq = tid >> 6;
  float acc[8] = {};
  const float* fb = sq + (size_t)b*BLKE;
  for (int sb = 0; sb < 4; sb++){
    #pragma unroll
    for (int j = 0; j < 8; j++){
      int idx = tid + j*256; int s = idx >> 6, x = idx & 63;
      LF[s][x] = fb[(size_t)(sb*32+s)*4096 + xt*64 + x];
    }
    #pragma unroll
    for (int j = 0; j < 4; j++){
      int idx = tid + j*256; int trow = idx >> 5, s = idx & 31;
      LM[trow][s] = mtxi[(tt*32+trow)*128 + sb*32+s];
    }
    __syncthreads();
    for (int s = 0; s < 32; s++){
      float f = LF[s][xx];
      #pragma unroll
      for (int i = 0; i < 8; i++) acc[i] += LM[tq*8+i][s]*f;
    }
    __syncthreads();
  }
  #pragma unroll
  for (int i = 0; i < 8; i++){
    int t = tt*32 + tq*8 + i;
    out[(size_t)b*BLKE + (size_t)t*4096 + xt*64+xx] = acc[i];
  }
}

extern "C" void kernel_launch(void* const* d_in, const int* in_sizes, int n_in,
                              void* d_out, int out_size, void* d_ws, size_t ws_size,
                              hipStream_t stream){
  const float* feature = (const float*)d_in[0];
  const float* convW   = (const float*)d_in[1];
  const float* convB   = (const float*)d_in[2];
  const float* wave    = (const float*)d_in[3];
  const float* Kr      = (const float*)d_in[4];
  const float* Ki      = (const float*)d_in[5];
  const float* mtx     = (const float*)d_in[6];
  const float* mtxi    = (const float*)d_in[7];
  float* out = (float*)d_out;
  float* ws  = (float*)d_ws;

  float*  M    = ws;                         // 32768
  float*  pA   = ws + 32832;                 // 2560
  float*  pB   = ws + 35392;                 // 512
  float*  pC   = ws + 35904;                 // 512
  float*  pD   = ws + 36416;                 // 512
  float*  tmp  = ws + 65536;                 // 2097152
  float*  sq   = ws + 65536 + 2097152;       // 1048576
  float2* Z2   = (float2*)(ws + 3211264);    // 2 * TCROP float2 (33.5 MB)
  float2* U2   = (float2*)(ws + 11599872);   // 2 * TCROP float2
  float2* V2   = (float2*)(ws + 19988480);   // 2 * TCROP float2
  float2* Wc   = (float2*)(ws + 28377088);   // VOLE float2 (33.5 MB)
  // Lw/Hw alias U2 (consumed by D2-D4 before kTfused writes U2)
  float*  Lw   = (float*)U2;                 // 2*BLKE
  float*  Hw   = ((float*)U2) + 1048576;     // 2*BLKE

  kD1 <<<640,  256, 0, stream>>>(mtx, wave, M, Kr, Ki, Lw, Hw, pA);
  kD2 <<<1024, 256, 0, stream>>>(feature, M, tmp, pA, Lw, pB, convW, convB);
  kD3 <<<4608, 256, 0, stream>>>(tmp, Z2, pA, pB, Lw, pC, convW, convB);
  kD4 <<<2560, 256, 0, stream>>>(Z2, pA, pC, Hw, pD, convW, convB);
  kWcF<<<4096, 256, 0, stream>>>(Kr, Ki, pA, pB, pC, pD, convW, convB, Wc);
  kTfused<<<dim3(1024,2), 256, 0, stream>>>(Z2, U2, V2, Wc);
  kHi<<<dim3(1024,2,2), 256, 0, stream>>>(U2, V2);
  kI3C<<<dim3(2048,2), 256, 0, stream>>>(U2, V2, sq);
  kOut<<<dim3(64,4,2), 256, 0, stream>>>(sq, mtxi, out);
}

// Round 12
// 273.277 us; speedup vs baseline: 1.0441x; 1.0441x over previous
//
#include <hip/hip_runtime.h>

#define BLKE 524288      // 128*64*64
#define VOLE 4194304     // 256*128*128
#define TCROP 2097152    // 128*128*128 (t<128 compact complex volume)
#define PI2 6.283185307179586476925286766559

__device__ __forceinline__ float2 cmulf(float2 a, float2 b){
  return make_float2(a.x*b.x - a.y*b.y, a.x*b.y + a.y*b.x);
}
__device__ __forceinline__ float waveSum(float v){
  #pragma unroll
  for (int o=32;o;o>>=1) v += __shfl_xor(v,o);
  return v;
}
__device__ __forceinline__ float waveMaxf(float v){
  #pragma unroll
  for (int o=32;o;o>>=1) v = fmaxf(v,__shfl_xor(v,o));
  return v;
}
__device__ __forceinline__ float waveMinf(float v){
  #pragma unroll
  for (int o=32;o;o>>=1) v = fminf(v,__shfl_xor(v,o));
  return v;
}

// Reduce pA[kappa][256][5] redundantly (identical FP order in every block).
__device__ __forceinline__ void bcastReduce5(const float* __restrict__ pA, int kap,
    float& sum, float& mnl, float& mxl, float& mnh, float& mxh, float* sm /*>=20*/){
  int tid = threadIdx.x;
  const float* q = pA + kap*1280 + tid*5;
  float s = q[0], a = q[1], b = q[2], c = q[3], d = q[4];
  s = waveSum(s); a = waveMinf(a); b = waveMaxf(b); c = waveMinf(c); d = waveMaxf(d);
  if ((tid&63)==0){ int w = tid>>6; sm[w]=s; sm[4+w]=a; sm[8+w]=b; sm[12+w]=c; sm[16+w]=d; }
  __syncthreads();
  sum = sm[0]+sm[1]+sm[2]+sm[3];
  mnl = fminf(fminf(sm[4],sm[5]),fminf(sm[6],sm[7]));
  mxl = fmaxf(fmaxf(sm[8],sm[9]),fmaxf(sm[10],sm[11]));
  mnh = fminf(fminf(sm[12],sm[13]),fminf(sm[14],sm[15]));
  mxh = fmaxf(fmaxf(sm[16],sm[17]),fmaxf(sm[18],sm[19]));
}

__device__ __forceinline__ float bcastSum256(const float* __restrict__ p, float* sm /*>=4*/){
  int tid = threadIdx.x;
  float s = waveSum(p[tid]);
  if ((tid&63)==0) sm[tid>>6] = s;
  __syncthreads();
  return sm[0]+sm[1]+sm[2]+sm[3];
}

// ============ D1: attention pass A (blocks 0..511) || kM (512..639) ==========
__global__ void __launch_bounds__(256) kD1(const float* __restrict__ mtx,
                                           const float* __restrict__ wave,
                                           float* __restrict__ M,
                                           const float* __restrict__ Kr,
                                           const float* __restrict__ Ki,
                                           float* __restrict__ Lw, float* __restrict__ Hw,
                                           float* __restrict__ pA){
  __shared__ float spe[128];
  __shared__ float sm[20];
  int bid = blockIdx.x;
  int tid = threadIdx.x;
  if (bid < 512){
    int kap = bid >> 8, bx = bid & 255;
    const float* K = kap ? Ki : Kr;
    if (tid < 128) spe[tid] = sinf((float)tid);
    __syncthreads();
    float sum=0.f, mnl=3.4e38f, mxl=-3.4e38f, mnh=3.4e38f, mxh=-3.4e38f;
    int base = bx*256 + tid;
    #pragma unroll
    for (int it = 0; it < 8; it++){
      int e = base + it*65536;
      int tau = e >> 12, rem = e & 4095, eta = rem >> 6, om = rem & 63;
      float pe = spe[tau];
      float lo = K[(size_t)((tau+192)&255)*16384 + ((eta+96)&127)*128 + ((om+96)&127)];
      float hi = K[(size_t)(tau+64)*16384 + (eta+32)*128 + (om+32)];
      sum += lo;
      float lp = lo+pe, hp = hi+pe;
      Lw[kap*BLKE + e] = lp;
      Hw[kap*BLKE + e] = hp;
      mnl=fminf(mnl,lp); mxl=fmaxf(mxl,lp);
      mnh=fminf(mnh,hp); mxh=fmaxf(mxh,hp);
    }
    sum = waveSum(sum); mnl=waveMinf(mnl); mxl=waveMaxf(mxl); mnh=waveMinf(mnh); mxh=waveMaxf(mxh);
    if ((tid&63)==0){ int w=tid>>6; sm[w]=sum; sm[4+w]=mnl; sm[8+w]=mxl; sm[12+w]=mnh; sm[16+w]=mxh; }
    __syncthreads();
    if (tid==0){
      float* o = pA + kap*1280 + bx*5;
      o[0] = sm[0]+sm[1]+sm[2]+sm[3];
      o[1] = fminf(fminf(sm[4],sm[5]),fminf(sm[6],sm[7]));
      o[2] = fmaxf(fmaxf(sm[8],sm[9]),fmaxf(sm[10],sm[11]));
      o[3] = fminf(fminf(sm[12],sm[13]),fminf(sm[14],sm[15]));
      o[4] = fmaxf(fmaxf(sm[16],sm[17]),fmaxf(sm[18],sm[19]));
    }
  } else {
    int idx = (bid-512)*256 + tid;      // 32768 = 2*128*128
    int o = idx >> 14, r = idx & 16383;
    int t = r >> 7, s = r & 127;
    float acc = 0.f;
    int mlo = s-31; if (mlo < 0) mlo = 0;
    int mhi = s+31; if (mhi > 127) mhi = 127;
    for (int m = mlo; m <= mhi; m++) acc += mtx[t*128+m]*wave[o*63 + (s-m+31)];
    M[idx] = acc;
  }
}

// ============ D2: pass B (0..511) || kTmp (512..1023) ========================
__global__ void __launch_bounds__(256) kD2(const float* __restrict__ feat,
                                           const float* __restrict__ M,
                                           float* __restrict__ tmp,
                                           const float* __restrict__ pA,
                                           const float* __restrict__ Lw,
                                           float* __restrict__ pB,
                                           const float* cw, const float* cb){
  __shared__ __align__(16) char smem[16640];
  __shared__ float sm[20], smo[4];
  int bid = blockIdx.x;
  int tid = threadIdx.x;
  if (bid < 512){
    int kap = bid >> 8, bx = bid & 255;
    float sum,mnl,mxl,mnh,mxh;
    bcastReduce5(pA,kap,sum,mnl,mxl,mnh,mxh,sm);
    float w = cw[0], b = cb[0];
    float s1 = w*(sum*(1.0f/BLKE)) + b;
    float a1 = s1*w, c1 = s1*b;
    float mx = (a1>=0.f) ? a1*mxl+c1 : a1*mnl+c1;
    float acc = 0.f;
    int base = kap*BLKE + bx*256 + tid;
    #pragma unroll
    for (int it = 0; it < 8; it++){
      float lp = Lw[base + it*65536];
      acc += expf(a1*lp + c1 - mx);
    }
    acc = waveSum(acc);
    if ((tid&63)==0) smo[tid>>6] = acc;
    __syncthreads();
    if (tid==0) pB[kap*256 + bx] = smo[0]+smo[1]+smo[2]+smo[3];
  } else {
    int e = bid - 512;                  // 512 : b(2) x tt(4) x xt(64)
    int b = e >> 8, tt = (e >> 6) & 3, xt = e & 63;
    float (*LF)[64] = (float(*)[64])smem;
    float (*LM)[32][33] = (float(*)[32][33])(smem + 8192);
    int xx = tid & 63, tq = tid >> 6;
    float acc0[8] = {}, acc1[8] = {};
    const float* fb = feat + (size_t)b*BLKE;
    for (int sb = 0; sb < 4; sb++){
      #pragma unroll
      for (int j = 0; j < 8; j++){
        int idx = tid + j*256; int s = idx >> 6, x = idx & 63;
        LF[s][x] = fb[(size_t)(sb*32+s)*4096 + xt*64 + x];
      }
      #pragma unroll
      for (int j = 0; j < 8; j++){
        int idx = tid + j*256; int o = idx >> 10, r = idx & 1023;
        int trow = r >> 5, s = r & 31;
        LM[o][trow][s] = M[o*16384 + (tt*32+trow)*128 + sb*32+s];
      }
      __syncthreads();
      for (int s = 0; s < 32; s++){
        float f = LF[s][xx];
        #pragma unroll
        for (int i = 0; i < 8; i++){
          acc0[i] += LM[0][tq*8+i][s]*f;
          acc1[i] += LM[1][tq*8+i][s]*f;
        }
      }
      __syncthreads();
    }
    #pragma unroll
    for (int i = 0; i < 8; i++){
      int t = tt*32 + tq*8 + i;
      tmp[(size_t)(0*2+b)*BLKE + (size_t)t*4096 + xt*64+xx] = acc0[i];
      tmp[(size_t)(1*2+b)*BLKE + (size_t)t*4096 + xt*64+xx] = acc1[i];
    }
  }
}

// ============ D3: pass C (0..511) || kF1 (512..4607) =========================
__global__ void __launch_bounds__(256) kD3(const float* __restrict__ tmp,
                                           float2* __restrict__ Z2,
                                           const float* __restrict__ pA,
                                           const float* __restrict__ pB,
                                           const float* __restrict__ Lw,
                                           float* __restrict__ pC,
                                           const float* cw, const float* cb){
  __shared__ __align__(16) char smem[8832];
  __shared__ float sm[20], smB[4], smo[4];
  int bid = blockIdx.x;
  int tid = threadIdx.x;
  if (bid < 512){
    int kap = bid >> 8, bx = bid & 255;
    float sum,mnl,mxl,mnh,mxh;
    bcastReduce5(pA,kap,sum,mnl,mxl,mnh,mxh,sm);
    float d1 = bcastSum256(pB + kap*256, smB);
    float w = cw[0], b = cb[0];
    float s1 = w*(sum*(1.0f/BLKE)) + b;
    float a1 = s1*w, c1 = s1*b;
    float mx = (a1>=0.f) ? a1*mxl+c1 : a1*mnl+c1;
    float invd = 1.0f/d1;
    float acc = 0.f;
    int base = kap*BLKE + bx*256 + tid;
    #pragma unroll
    for (int it = 0; it < 8; it++){
      float lp = Lw[base + it*65536];
      float p = expf(a1*lp + c1 - mx)*invd;
      acc += lp/(1.f + expf(-p));
    }
    acc = waveSum(acc);
    if ((tid&63)==0) smo[tid>>6] = acc;
    __syncthreads();
    if (tid==0) pC[kap*256 + bx] = smo[0]+smo[1]+smo[2]+smo[3];
  } else {
    int e = bid - 512;                  // 4096 : b(2) x 2048 line-groups
    int b = e >> 11, bx = e & 2047;
    float2 (*bA)[130] = (float2(*)[130])smem;
    float2 (*bB)[130] = (float2(*)[130])(smem + 4160);
    float2* tw = (float2*)(smem + 8320);
    if (tid < 64){
      double ang = -PI2 * (double)tid / 128.0;
      tw[tid] = make_float2((float)cos(ang), (float)sin(ang));
    }
    int l = tid >> 6, lane = tid & 63;
    int line = bx*4 + l;
    int t = line >> 6, h = line & 63;
    const float* pc = tmp + (size_t)b*BLKE + (size_t)t*4096 + h*64;
    const float* ps = tmp + (size_t)(2+b)*BLKE + (size_t)t*4096 + h*64;
    bA[l][lane] = make_float2(pc[lane], ps[lane]);
    bA[l][lane+64] = make_float2(0.f, 0.f);
    __syncthreads();
    float2 (*src)[130] = bA, (*dst)[130] = bB;
    int m = 1;
    #pragma unroll
    for (int st = 0; st < 7; st++){
      int i = lane;
      int jm = i & ~(m-1);
      float2 a = src[l][i], b2 = src[l][i+64];
      float2 s = make_float2(a.x+b2.x, a.y+b2.y);
      float2 d = make_float2(a.x-b2.x, a.y-b2.y);
      dst[l][i+jm]   = s;
      dst[l][i+jm+m] = cmulf(d, tw[jm]);
      __syncthreads();
      float2 (*tp)[130] = src; src = dst; dst = tp;
      m <<= 1;
    }
    float2* outp = Z2 + (size_t)b*TCROP + (size_t)t*16384 + (size_t)h*128;
    outp[lane]    = src[l][lane];
    outp[lane+64] = src[l][lane+64];
  }
}

// ============ D4: pass D (0..511) || kHf (512..2559) =========================
__global__ void __launch_bounds__(256) kD4(float2* __restrict__ Z2,
                                           const float* __restrict__ pA,
                                           const float* __restrict__ pC,
                                           const float* __restrict__ Hw,
                                           float* __restrict__ pD,
                                           const float* cw, const float* cb){
  __shared__ __align__(16) char smem[33792];
  __shared__ float sm[20], smC[4], smo[4];
  int bid = blockIdx.x;
  int tid = threadIdx.x;
  if (bid < 512){
    int kap = bid >> 8, bx = bid & 255;
    float sum,mnl,mxl,mnh,mxh;
    bcastReduce5(pA,kap,sum,mnl,mxl,mnh,mxh,sm);
    float sl2 = bcastSum256(pC + kap*256, smC);
    float w = cw[0], b = cb[0];
    float s2 = w*(sl2*(1.0f/BLKE)) + b;
    float a2 = s2*w, c2 = s2*b;
    float mx = (a2>=0.f) ? a2*mxh+c2 : a2*mnh+c2;
    float acc = 0.f;
    int base = kap*BLKE + bx*256 + tid;
    #pragma unroll
    for (int it = 0; it < 8; it++){
      float hp = Hw[base + it*65536];
      acc += expf(a2*hp + c2 - mx);
    }
    acc = waveSum(acc);
    if ((tid&63)==0) smo[tid>>6] = acc;
    __syncthreads();
    if (tid==0) pD[kap*256 + bx] = smo[0]+smo[1]+smo[2]+smo[3];
  } else {
    int e = bid - 512;                  // 2048 : b(2) x 1024
    int b = e >> 10, bx = e & 1023;
    float2 (*bA)[130] = (float2(*)[130])smem;
    float2 (*bB)[130] = (float2(*)[130])(smem + 16640);
    float2* tw = (float2*)(smem + 33280);
    if (tid < 64){
      double ang = -PI2 * (double)tid / 128.0;
      tw[tid] = make_float2((float)cos(ang), (float)sin(ang));
    }
    float2* Z = Z2 + (size_t)b*TCROP;
    int t = bx >> 3; int w0 = (bx & 7) << 4;
    size_t base = (size_t)t*16384 + w0;
    #pragma unroll
    for (int q = 0; q < 4; q++){
      int idx = q*256 + tid; int wl = idx & 15, hh = idx >> 4;
      bA[wl][hh] = Z[base + (size_t)hh*128 + wl];
      bA[wl][hh+64] = make_float2(0.f, 0.f);
    }
    __syncthreads();
    float2 (*src)[130] = bA, (*dst)[130] = bB;
    int m = 1;
    #pragma unroll
    for (int st = 0; st < 7; st++){
      #pragma unroll
      for (int q = 0; q < 4; q++){
        int g = q*256 + tid; int li = g >> 6; int i = g & 63;
        int jm = i & ~(m-1);
        float2 a = src[li][i], b2 = src[li][i+64];
        float2 s = make_float2(a.x+b2.x, a.y+b2.y);
        float2 d = make_float2(a.x-b2.x, a.y-b2.y);
        dst[li][i+jm]   = s;
        dst[li][i+jm+m] = cmulf(d, tw[jm]);
      }
      __syncthreads();
      float2 (*tp)[130] = src; src = dst; dst = tp;
      m <<= 1;
    }
    #pragma unroll
    for (int q = 0; q < 8; q++){
      int idx = q*256 + tid; int wl = idx & 15, hh = idx >> 4;
      Z[base + (size_t)hh*128 + wl] = src[wl][hh];
    }
  }
}

// ---------------- attention helpers ----------------
__device__ __forceinline__ float attnv(float v, float a, float c, float mx, float invd){
  float p = expf(a*v + c - mx)*invd;
  return v / (1.f + expf(-p));
}
__device__ __forceinline__ float2 wcAt(int t, int h, int w,
                                       const float* __restrict__ Kr, const float* __restrict__ Ki,
                                       const float* spe, const float* P){
  size_t off = (size_t)t*16384 + (size_t)h*128 + w;
  float kr = Kr[off], ki = Ki[off];
  bool center = (t>=64 && t<192) && (h>=32 && h<96) && (w>=32 && w<96);
  int tc = (t+64)&255, hc = (h+32)&127, wc = (w+32)&127;
  bool corner = (tc<128) && (hc<64) && (wc<64);
  float2 o;
  if (center){
    float pe = spe[t-64];
    o.x = attnv(kr+pe, P[4],  P[5],  P[6],  P[7]);
    o.y = attnv(ki+pe, P[12], P[13], P[14], P[15]);
  } else if (corner){
    float pe = spe[tc];
    o.x = attnv(kr+pe, P[0], P[1],  P[2],  P[3]);
    o.y = attnv(ki+pe, P[8], P[9],  P[10], P[11]);
  } else {
    o.x = kr; o.y = ki;
  }
  return o;
}

// ======== D5: finalize scalars inline (redundant per block) + Wc volume ======
__global__ void __launch_bounds__(256) kWcF(const float* __restrict__ Kr,
                                            const float* __restrict__ Ki,
                                            const float* __restrict__ pA,
                                            const float* __restrict__ pB,
                                            const float* __restrict__ pC,
                                            const float* __restrict__ pD,
                                            const float* cw, const float* cb,
                                            float2* __restrict__ Wc){
  __shared__ float spe[128];
  __shared__ float P[16];
  __shared__ float sm[20], smB[4], smC[4], smD[4];
  int tid = threadIdx.x;
  if (tid < 128) spe[tid] = sinf((float)tid);
  for (int kap = 0; kap < 2; kap++){
    if (kap) __syncthreads();
    float sum,mnl,mxl,mnh,mxh;
    bcastReduce5(pA,kap,sum,mnl,mxl,mnh,mxh,sm);
    float d1  = bcastSum256(pB + kap*256, smB);
    float sl2 = bcastSum256(pC + kap*256, smC);
    float d2  = bcastSum256(pD + kap*256, smD);
    if (tid==0){
      float w = cw[0], b = cb[0];
      float s1 = w*(sum*(1.0f/BLKE)) + b;
      float a1 = s1*w, c1 = s1*b;
      float mx1 = (a1>=0.f) ? a1*mxl+c1 : a1*mnl+c1;
      float s2 = w*(sl2*(1.0f/BLKE)) + b;
      float a2 = s2*w, c2 = s2*b;
      float mx2 = (a2>=0.f) ? a2*mxh+c2 : a2*mnh+c2;
      float* Q = P + kap*8;
      Q[0]=a1; Q[1]=c1; Q[2]=mx1; Q[3]=1.0f/d1;
      Q[4]=a2; Q[5]=c2; Q[6]=mx2; Q[7]=1.0f/d2;
    }
  }
  __syncthreads();
  #pragma unroll
  for (int q = 0; q < 4; q++){
    int idx = blockIdx.x*1024 + q*256 + tid;   // VOLE over 4096 blocks
    int t = idx >> 14, r = idx & 16383, h = r >> 7, w = r & 127;
    Wc[idx] = wcAt(t, h, w, Kr, Ki, spe, P);
  }
}

// ---- fused fwd-T(256) + multiply + 2x inv-T, radix-4 in-place --------------
__global__ void __launch_bounds__(256) kTfused(const float2* __restrict__ Z2,
                                               float2* __restrict__ U2,
                                               float2* __restrict__ V2,
                                               const float2* __restrict__ Wc){
  __shared__ float2 buf[16][259];
  __shared__ float2 tw[256];
  int tid = threadIdx.x;
  {
    double ang = -PI2 * (double)tid / 256.0;
    tw[tid] = make_float2((float)cos(ang), (float)sin(ang));
  }
  int b = blockIdx.y;
  int bid = blockIdx.x;                 // 1024 : 128 h x 8 w-tiles(16)
  int h = bid >> 3, w0 = (bid & 7) << 4;
  int wl = tid & 15, pq = tid >> 4;
  const float2* Z = Z2 + (size_t)b*TCROP;
  size_t gbase = (size_t)h*128 + w0 + wl;
  #pragma unroll
  for (int q = 0; q < 8; q++){
    int p = q*16 + pq;
    buf[wl][p] = Z[(size_t)p*16384 + gbase];
    buf[wl][p+128] = make_float2(0.f, 0.f);
  }
  __syncthreads();
  #pragma unroll
  for (int st = 0; st < 4; st++){
    const int Q = 64 >> (2*st);
    const int f = 1 << (2*st);
    #pragma unroll
    for (int it = 0; it < 4; it++){
      int u = pq + 16*it;
      int j = u & (Q-1);
      int seg = u >> (6 - 2*st);
      int base = (seg << (8 - 2*st)) + j;
      float2 a0 = buf[wl][base];
      float2 a1 = buf[wl][base+Q];
      float2 a2 = buf[wl][base+2*Q];
      float2 a3 = buf[wl][base+3*Q];
      float2 t0 = make_float2(a0.x+a2.x, a0.y+a2.y);
      float2 t1 = make_float2(a0.x-a2.x, a0.y-a2.y);
      float2 t2 = make_float2(a1.x+a3.x, a1.y+a3.y);
      float2 t3 = make_float2(a1.x-a3.x, a1.y-a3.y);
      float2 z0 = make_float2(t0.x+t2.x, t0.y+t2.y);
      float2 z2 = make_float2(t0.x-t2.x, t0.y-t2.y);
      float2 z1 = make_float2(t1.x+t3.y, t1.y-t3.x);
      float2 z3 = make_float2(t1.x-t3.y, t1.y+t3.x);
      buf[wl][base]     = z0;
      buf[wl][base+Q]   = cmulf(z1, tw[f*j]);
      buf[wl][base+2*Q] = cmulf(z2, tw[2*f*j]);
      buf[wl][base+3*Q] = cmulf(z3, tw[3*f*j]);
    }
    __syncthreads();
  }
  float2 rg[16];
  #pragma unroll
  for (int q = 0; q < 16; q++) rg[q] = buf[wl][q*16 + pq];
  #pragma unroll
  for (int q = 0; q < 16; q++){
    int p = q*16 + pq;
    int kt = ((p&3)<<6) | (((p>>2)&3)<<4) | (((p>>4)&3)<<2) | ((p>>6)&3);
    float2 wc = Wc[(size_t)kt*16384 + (size_t)h*128 + w0 + wl];
    buf[wl][p] = cmulf(rg[q], wc);
  }
  __syncthreads();
  #pragma unroll
  for (int st = 0; st < 4; st++){
    const int Q = 1 << (2*st);
    const int f = 64 >> (2*st);
    #pragma unroll
    for (int it = 0; it < 4; it++){
      int u = pq + 16*it;
      int j = u & (Q-1);
      int seg = u >> (2*st);
      int base = (seg << (2*st + 2)) + j;
      float2 w1 = tw[f*j], w2 = tw[2*f*j], w3 = tw[3*f*j];
      float2 a0 = buf[wl][base];
      float2 r1 = buf[wl][base+Q];
      float2 r2 = buf[wl][base+2*Q];
      float2 r3 = buf[wl][base+3*Q];
      float2 b1 = make_float2(r1.x*w1.x + r1.y*w1.y, r1.y*w1.x - r1.x*w1.y);
      float2 b2 = make_float2(r2.x*w2.x + r2.y*w2.y, r2.y*w2.x - r2.x*w2.y);
      float2 b3 = make_float2(r3.x*w3.x + r3.y*w3.y, r3.y*w3.x - r3.x*w3.y);
      float2 t0 = make_float2(a0.x+b2.x, a0.y+b2.y);
      float2 t1 = make_float2(a0.x-b2.x, a0.y-b2.y);
      float2 t2 = make_float2(b1.x+b3.x, b1.y+b3.y);
      float2 t3 = make_float2(b1.x-b3.x, b1.y-b3.y);
      buf[wl][base]     = make_float2(t0.x+t2.x, t0.y+t2.y);
      buf[wl][base+Q]   = make_float2(t1.x-t3.y, t1.y+t3.x);
      buf[wl][base+2*Q] = make_float2(t0.x-t2.x, t0.y-t2.y);
      buf[wl][base+3*Q] = make_float2(t1.x+t3.y, t1.y-t3.x);
    }
    __syncthreads();
  }
  float2* Uo = U2 + (size_t)b*TCROP;
  #pragma unroll
  for (int q = 0; q < 8; q++){
    int p = q*16 + pq;
    Uo[(size_t)p*16384 + gbase] = buf[wl][p];
  }
  #pragma unroll
  for (int q = 0; q < 16; q++){
    int p = q*16 + pq;
    int kt = ((p&3)<<6) | (((p>>2)&3)<<4) | (((p>>4)&3)<<2) | ((p>>6)&3);
    int tm = (256-kt)&255, hm = (128-h)&127, wm = (128-(w0+wl))&127;
    float2 wc = Wc[(size_t)tm*16384 + (size_t)hm*128 + wm];
    wc.y = -wc.y;
    buf[wl][p] = cmulf(rg[q], wc);
  }
  __syncthreads();
  #pragma unroll
  for (int st = 0; st < 4; st++){
    const int Q = 1 << (2*st);
    const int f = 64 >> (2*st);
    #pragma unroll
    for (int it = 0; it < 4; it++){
      int u = pq + 16*it;
      int j = u & (Q-1);
      int seg = u >> (2*st);
      int base = (seg << (2*st + 2)) + j;
      float2 w1 = tw[f*j], w2 = tw[2*f*j], w3 = tw[3*f*j];
      float2 a0 = buf[wl][base];
      float2 r1 = buf[wl][base+Q];
      float2 r2 = buf[wl][base+2*Q];
      float2 r3 = buf[wl][base+3*Q];
      float2 b1 = make_float2(r1.x*w1.x + r1.y*w1.y, r1.y*w1.x - r1.x*w1.y);
      float2 b2 = make_float2(r2.x*w2.x + r2.y*w2.y, r2.y*w2.x - r2.x*w2.y);
      float2 b3 = make_float2(r3.x*w3.x + r3.y*w3.y, r3.y*w3.x - r3.x*w3.y);
      float2 t0 = make_float2(a0.x+b2.x, a0.y+b2.y);
      float2 t1 = make_float2(a0.x-b2.x, a0.y-b2.y);
      float2 t2 = make_float2(b1.x+b3.x, b1.y+b3.y);
      float2 t3 = make_float2(b1.x-b3.x, b1.y-b3.y);
      buf[wl][base]     = make_float2(t0.x+t2.x, t0.y+t2.y);
      buf[wl][base+Q]   = make_float2(t1.x-t3.y, t1.y+t3.x);
      buf[wl][base+2*Q] = make_float2(t0.x-t2.x, t0.y-t2.y);
      buf[wl][base+3*Q] = make_float2(t1.x+t3.y, t1.y-t3.x);
    }
    __syncthreads();
  }
  float2* Vo = V2 + (size_t)b*TCROP;
  #pragma unroll
  for (int q = 0; q < 8; q++){
    int p = q*16 + pq;
    Vo[(size_t)p*16384 + gbase] = buf[wl][p];
  }
}

// ---------------- H-axis inverse (N=128) on compact buffers: grid (1024,b,uv)
__global__ void __launch_bounds__(256) kHi(float2* __restrict__ U2, float2* __restrict__ V2){
  __shared__ float2 bA[16][130], bB[16][130], tw[64];
  int tid = threadIdx.x;
  if (tid < 64){
    double ang = PI2 * (double)tid / 128.0;
    tw[tid] = make_float2((float)cos(ang), (float)sin(ang));
  }
  float2* Z = (blockIdx.z ? V2 : U2) + (size_t)blockIdx.y*TCROP;
  int bid = blockIdx.x;
  int t = bid >> 3; int w0 = (bid & 7) << 4;
  size_t base = (size_t)t*16384 + w0;
  #pragma unroll
  for (int q = 0; q < 8; q++){
    int idx = q*256 + tid; int wl = idx & 15, hh = idx >> 4;
    bA[wl][hh] = Z[base + (size_t)hh*128 + wl];
  }
  __syncthreads();
  float2 (*src)[130] = bA, (*dst)[130] = bB;
  int m = 1;
  #pragma unroll
  for (int st = 0; st < 7; st++){
    #pragma unroll
    for (int q = 0; q < 4; q++){
      int g = q*256 + tid; int li = g >> 6; int i = g & 63;
      int jm = i & ~(m-1);
      float2 a = src[li][i], b2 = src[li][i+64];
      float2 s = make_float2(a.x+b2.x, a.y+b2.y);
      float2 d = make_float2(a.x-b2.x, a.y-b2.y);
      dst[li][i+jm]   = s;
      dst[li][i+jm+m] = cmulf(d, tw[jm]);
    }
    __syncthreads();
    float2 (*tp)[130] = src; src = dst; dst = tp;
    m <<= 1;
  }
  #pragma unroll
  for (int q = 0; q < 4; q++){
    int idx = q*256 + tid; int wl = idx & 15, hh = idx >> 4;   // hh < 64
    Z[base + (size_t)hh*128 + wl] = src[wl][hh];
  }
}

// -- fused W-axis inverse + combine: per line FFT U then V; s=y*conj(v)*sc^2 --
__global__ void __launch_bounds__(256) kI3C(const float2* __restrict__ U2,
                                            const float2* __restrict__ V2,
                                            float* __restrict__ sq){
  __shared__ float2 bA[4][130], bB[4][130], tw[64];
  int tid = threadIdx.x;
  if (tid < 64){
    double ang = PI2 * (double)tid / 128.0;
    tw[tid] = make_float2((float)cos(ang), (float)sin(ang));
  }
  int b = blockIdx.y;
  int l = tid >> 6, lane = tid & 63;
  int line = blockIdx.x*4 + l;         // t<128, h<64
  int t = line >> 6, h = line & 63;
  size_t off = (size_t)b*TCROP + (size_t)t*16384 + (size_t)h*128;
  bA[l][lane]    = U2[off + lane];
  bA[l][lane+64] = U2[off + lane + 64];
  __syncthreads();
  float2 (*src)[130] = bA, (*dst)[130] = bB;
  int m = 1;
  #pragma unroll
  for (int st = 0; st < 7; st++){
    int i = lane;
    int jm = i & ~(m-1);
    float2 a = src[l][i], b2 = src[l][i+64];
    float2 s = make_float2(a.x+b2.x, a.y+b2.y);
    float2 d = make_float2(a.x-b2.x, a.y-b2.y);
    dst[l][i+jm]   = s;
    dst[l][i+jm+m] = cmulf(d, tw[jm]);
    __syncthreads();
    float2 (*tp)[130] = src; src = dst; dst = tp;
    m <<= 1;
  }
  float2 y = src[l][lane];
  dst[l][lane]    = V2[off + lane];
  dst[l][lane+64] = V2[off + lane + 64];
  __syncthreads();
  src = dst; dst = (src == bA) ? bB : bA;
  m = 1;
  #pragma unroll
  for (int st = 0; st < 7; st++){
    int i = lane;
    int jm = i & ~(m-1);
    float2 a = src[l][i], b2 = src[l][i+64];
    float2 s = make_float2(a.x+b2.x, a.y+b2.y);
    float2 d = make_float2(a.x-b2.x, a.y-b2.y);
    dst[l][i+jm]   = s;
    dst[l][i+jm+m] = cmulf(d, tw[jm]);
    __syncthreads();
    float2 (*tp)[130] = src; src = dst; dst = tp;
    m <<= 1;
  }
  float2 v = src[l][lane];
  const float sc = 1.0f/(float)VOLE;
  const float sc2 = sc*sc;
  float2 s = cmulf(y, make_float2(v.x, -v.y));
  s.x *= sc2; s.y *= sc2;
  float mag = 0.5f*(sqrtf(s.x*s.x + s.y*s.y) + s.x);
  mag = fmaxf(mag, 0.f);
  sq[(size_t)b*BLKE + (size_t)t*4096 + h*64 + lane] = sqrtf(mag);
}

// ---------------- out[b][t][x] = sum_m mtxi[t][m]*sq[b][m][x] ----------------
__global__ void __launch_bounds__(256) kOut(const float* __restrict__ sq,
                                            const float* __restrict__ mtxi,
                                            float* __restrict__ out){
  __shared__ float LF[32][64];
  __shared__ float LM[32][33];
  int b = blockIdx.z, tt = blockIdx.y, xt = blockIdx.x;
  int tid = threadIdx.x;
  int xx = tid & 63, tq = tid >> 6;
  float acc[8] = {};
  const float* fb = sq + (size_t)b*BLKE;
  for (int sb = 0; sb < 4; sb++){
    #pragma unroll
    for (int j = 0; j < 8; j++){
      int idx = tid + j*256; int s = idx >> 6, x = idx & 63;
      LF[s][x] = fb[(size_t)(sb*32+s)*4096 + xt*64 + x];
    }
    #pragma unroll
    for (int j = 0; j < 4; j++){
      int idx = tid + j*256; int trow = idx >> 5, s = idx & 31;
      LM[trow][s] = mtxi[(tt*32+trow)*128 + sb*32+s];
    }
    __syncthreads();
    for (int s = 0; s < 32; s++){
      float f = LF[s][xx];
      #pragma unroll
      for (int i = 0; i < 8; i++) acc[i] += LM[tq*8+i][s]*f;
    }
    __syncthreads();
  }
  #pragma unroll
  for (int i = 0; i < 8; i++){
    int t = tt*32 + tq*8 + i;
    out[(size_t)b*BLKE + (size_t)t*4096 + xt*64+xx] = acc[i];
  }
}

extern "C" void kernel_launch(void* const* d_in, const int* in_sizes, int n_in,
                              void* d_out, int out_size, void* d_ws, size_t ws_size,
                              hipStream_t stream){
  const float* feature = (const float*)d_in[0];
  const float* convW   = (const float*)d_in[1];
  const float* convB   = (const float*)d_in[2];
  const float* wave    = (const float*)d_in[3];
  const float* Kr      = (const float*)d_in[4];
  const float* Ki      = (const float*)d_in[5];
  const float* mtx     = (const float*)d_in[6];
  const float* mtxi    = (const float*)d_in[7];
  float* out = (float*)d_out;
  float* ws  = (float*)d_ws;

  float*  M    = ws;                         // 32768
  float*  pA   = ws + 32832;                 // 2560
  float*  pB   = ws + 35392;                 // 512
  float*  pC   = ws + 35904;                 // 512
  float*  pD   = ws + 36416;                 // 512
  float*  tmp  = ws + 65536;                 // 2097152
  float*  sq   = ws + 65536 + 2097152;       // 1048576
  float2* Z2   = (float2*)(ws + 3211264);    // 2 * TCROP float2 (33.5 MB)
  float2* U2   = (float2*)(ws + 11599872);   // 2 * TCROP float2
  float2* V2   = (float2*)(ws + 19988480);   // 2 * TCROP float2
  float2* Wc   = (float2*)(ws + 28377088);   // VOLE float2 (33.5 MB)
  // Lw/Hw alias U2 (consumed by D2-D4 before kTfused writes U2)
  float*  Lw   = (float*)U2;                 // 2*BLKE
  float*  Hw   = ((float*)U2) + 1048576;     // 2*BLKE

  kD1 <<<640,  256, 0, stream>>>(mtx, wave, M, Kr, Ki, Lw, Hw, pA);
  kD2 <<<1024, 256, 0, stream>>>(feature, M, tmp, pA, Lw, pB, convW, convB);
  kD3 <<<4608, 256, 0, stream>>>(tmp, Z2, pA, pB, Lw, pC, convW, convB);
  kD4 <<<2560, 256, 0, stream>>>(Z2, pA, pC, Hw, pD, convW, convB);
  kWcF<<<4096, 256, 0, stream>>>(Kr, Ki, pA, pB, pC, pD, convW, convB, Wc);
  kTfused<<<dim3(1024,2), 256, 0, stream>>>(Z2, U2, V2, Wc);
  kHi<<<dim3(1024,2,2), 256, 0, stream>>>(U2, V2);
  kI3C<<<dim3(2048,2), 256, 0, stream>>>(U2, V2, sq);
  kOut<<<dim3(64,4,2), 256, 0, stream>>>(sq, mtxi, out);
}